// Round 11
// baseline (2501.758 us; speedup 1.0000x reference)
//
#include <hip/hip_runtime.h>

#define T_STEPS 4096
#define BATCH   64
#define INDIM   4
#define H       256
#define OUTD    2
#define CHUNK   32
// h vector stored as 128 packed-half2 entries (entry e = rows 2e,2e+1),
// slot(e) = e + (e>>4)*4 spreads the 8 ko-groups across 8 distinct bank-quads
#define HSTRIDE 160
#define RING_DW (CHUNK*HSTRIDE)       // 5120 dwords (20 KB)
#define RING_B  (4*RING_DW)
#define DUMP_DW 512                   // 2 KB dump for non-writer lanes
#define WF_DW   (OUTD*(H/2))
// Pad total static LDS to 84 KB: >80 KB means at most ONE block per CU, so
// the register allocator's occupancy target becomes 16 waves/CU = 4/SIMD =
// 128-VGPR budget -> 32 weight dwords + working set fit WITHIN the target.
#define LDS_DW  21504                 // 86016 B = 84 KB

typedef __fp16 half2v __attribute__((ext_vector_type(2)));

__device__ __forceinline__ float fast_tanh(float x) {
    float ax = fabsf(x);
    float e  = __expf(-2.0f * ax);
    float r  = (1.0f - e) * __builtin_amdgcn_rcpf(1.0f + e);
    return copysignf(r, x);
}

// acc += dpp_shifted(acc). Validated in R8/R9/R10: row_shl-reduce lands the
// group sum at the LOWEST lane, row_shr at the HIGHEST (16-lane row scope).
template<int CTRL>
__device__ __forceinline__ float dpp_radd(float a) {
    int s = __builtin_amdgcn_update_dpp(0, __builtin_bit_cast(int, a),
                                        CTRL, 0xf, 0xf, true);
    return a + __builtin_bit_cast(float, s);
}
#define SHL1 0x101
#define SHL2 0x102
#define SHL4 0x104
#define SHL8 0x108
#define SHR1 0x111
#define SHR2 0x112
#define SHR4 0x114

// 1024 threads = 16 waves = 4 waves/SIMD (LDS-forced single block per CU).
// Thread owns 2 rows x 32 k (32 weight dwords). Ksplit=8, DPP reduce.
__global__ __attribute__((amdgpu_waves_per_eu(4, 4))) __launch_bounds__(1024)
void elman_kernel(const float* __restrict__ input,
                  const float* __restrict__ Wi,
                  const float* __restrict__ bi,
                  const float* __restrict__ Wh,
                  const float* __restrict__ bh,
                  const float* __restrict__ Wf,
                  const float* __restrict__ bf,
                  float* __restrict__ out)
{
    const int b  = blockIdx.x;
    const int t  = threadIdx.x;
    const int rp = t >> 3;        // row pair 0..127 (rows 2rp, 2rp+1)
    const int ko = t & 7;         // k-eighth: k in [32ko, 32ko+32)
    const int r0 = rp * 2, r1 = r0 + 1;
    const int k0 = ko * 32;

    __shared__ unsigned int lds[LDS_DW];
    unsigned int* ring  = lds;                    // [CHUNK][HSTRIDE]
    unsigned int* wf_pk = lds + RING_DW + DUMP_DW;

    // --- weights: 2 rows x 32 k packed f16 -> 32 dwords ---
    half2v w0[16], w1[16];
    {
        const float* p0 = Wh + (size_t)r0 * H + k0;
        const float* p1 = Wh + (size_t)r1 * H + k0;
        #pragma unroll
        for (int j = 0; j < 8; ++j) {
            float4 a = *(const float4*)(p0 + 4 * j);
            float4 c = *(const float4*)(p1 + 4 * j);
            w0[2 * j]     = __builtin_amdgcn_cvt_pkrtz(a.x, a.y);
            w0[2 * j + 1] = __builtin_amdgcn_cvt_pkrtz(a.z, a.w);
            w1[2 * j]     = __builtin_amdgcn_cvt_pkrtz(c.x, c.y);
            w1[2 * j + 1] = __builtin_amdgcn_cvt_pkrtz(c.z, c.w);
        }
    }
    #pragma unroll
    for (int j = 0; j < 16; ++j) {
        float f0 = __builtin_bit_cast(float, w0[j]);
        float f1 = __builtin_bit_cast(float, w1[j]);
        asm volatile("" : "+v"(f0), "+v"(f1));
        w0[j] = __builtin_bit_cast(half2v, f0);
        w1[j] = __builtin_bit_cast(half2v, f1);
    }

    // epilogue: lane ko==0 finalizes row r0 (lo half of packed dword),
    // lane ko==7 finalizes row r1 (hi half). Others write to dump.
    const int  is_hi    = (ko == 7);
    const int  is_wr    = (ko == 0) | is_hi;
    const int  row_mine = r0 + is_hi;
    const float4 wim    = *(const float4*)(Wi + row_mine * INDIM);
    const float  biasm  = bi[row_mine] + bh[row_mine];
    const float  bf0    = bf[0], bf1 = bf[1];
    const unsigned int slot_rp = rp + ((rp >> 4) << 2);     // slot_of(rp)
    const int  boff     = slot_rp * 4 + (is_hi ? 2 : 0);    // byte in entry
    const int  dumpoff  = RING_B + t * 2;

    if (t < WF_DW) {
        const int o = t >> 7, e = t & 127;
        wf_pk[t] = __builtin_bit_cast(unsigned int,
            __builtin_amdgcn_cvt_pkrtz(Wf[o * H + 2 * e], Wf[o * H + 2 * e + 1]));
    }
    if (t < H / 2) ring[(CHUNK - 1) * HSTRIDE + t + ((t >> 4) << 2)] = 0u; // h0=0
    __syncthreads();

    float4 xcur = *(const float4*)(input + (size_t)b * INDIM);  // step 0
    const unsigned int rd_off = (unsigned int)(20 * ko);        // slot(ko*16)

    for (int chunk = 0; chunk < T_STEPS / CHUNK; ++chunk) {
        #pragma unroll 1
        for (int i = 0; i < CHUNK; ++i) {
            const int step = chunk * CHUNK + i;
            int s2 = step + 1; if (s2 >= T_STEPS) s2 = T_STEPS - 1;
            float4 xnext = *(const float4*)(input + ((size_t)s2 * BATCH + b) * INDIM);

            // my 32-k segment of h (16 dwords): 4 b128, bank-disjoint across ko
            const unsigned int* hb =
                ring + ((i + CHUNK - 1) & (CHUNK - 1)) * HSTRIDE + rd_off;
            uint4 a0 = *(const uint4*)(hb + 0);
            uint4 a1 = *(const uint4*)(hb + 4);
            uint4 a2 = *(const uint4*)(hb + 8);
            uint4 a3 = *(const uint4*)(hb + 12);
            unsigned int hw[16] = {a0.x, a0.y, a0.z, a0.w,
                                   a1.x, a1.y, a1.z, a1.w,
                                   a2.x, a2.y, a2.z, a2.w,
                                   a3.x, a3.y, a3.z, a3.w};

            float acc0 = 0.f, acc1 = 0.f;
            #pragma unroll
            for (int j = 0; j < 16; ++j) {
                half2v hv = __builtin_bit_cast(half2v, hw[j]);
                acc0 = __builtin_amdgcn_fdot2(w0[j], hv, acc0, false);
                acc1 = __builtin_amdgcn_fdot2(w1[j], hv, acc1, false);
            }

            // DPP reduce over 8-lane group: acc0 -> lane 0, acc1 -> lane 7
            acc0 = dpp_radd<SHL4>(acc0);
            acc0 = dpp_radd<SHL2>(acc0);
            acc0 = dpp_radd<SHL1>(acc0);
            acc1 = dpp_radd<SHR4>(acc1);
            acc1 = dpp_radd<SHR2>(acc1);
            acc1 = dpp_radd<SHR1>(acc1);

            // unmasked epilogue: every lane finalizes one row (2 of 8 valid)
            float accm = is_hi ? acc1 : acc0;
            float pre  = accm + biasm +
                xcur.x * wim.x + xcur.y * wim.y + xcur.z * wim.z + xcur.w * wim.w;
            __fp16 h16 = (__fp16)fast_tanh(pre);
            int waddr  = is_wr ? (i * (HSTRIDE * 4) + boff) : dumpoff;
            *(__fp16*)((char*)lds + waddr) = h16;   // one ds_write_b16

            xcur = xnext;
            __syncthreads();
        }

        // --- deferred output head: 64 tasks x 16 lanes ---
        {
            const int task = t >> 4;     // (step-in-chunk, out-idx)
            const int s    = task >> 1;
            const int o    = task & 1;
            const int sub  = t & 15;     // 8-dword (16-k) segment
            const unsigned int* hp =
                ring + s * HSTRIDE + sub * 8 + ((sub >> 1) << 2);
            const unsigned int* wp = wf_pk + o * (H / 2) + sub * 8;

            uint4 hA = *(const uint4*)(hp);
            uint4 hB = *(const uint4*)(hp + 4);
            uint4 wA = *(const uint4*)(wp);
            uint4 wB = *(const uint4*)(wp + 4);
            unsigned int hh[8] = {hA.x, hA.y, hA.z, hA.w, hB.x, hB.y, hB.z, hB.w};
            unsigned int ww[8] = {wA.x, wA.y, wA.z, wA.w, wB.x, wB.y, wB.z, wB.w};

            float acc = 0.f;
            #pragma unroll
            for (int j = 0; j < 8; ++j)
                acc = __builtin_amdgcn_fdot2(__builtin_bit_cast(half2v, ww[j]),
                                             __builtin_bit_cast(half2v, hh[j]),
                                             acc, false);
            acc = dpp_radd<SHL8>(acc);
            acc = dpp_radd<SHL4>(acc);
            acc = dpp_radd<SHL2>(acc);
            acc = dpp_radd<SHL1>(acc);

            if (sub == 0) {
                out[((size_t)(chunk * CHUNK + s) * BATCH + b) * OUTD + o] =
                    fast_tanh(acc + (o ? bf1 : bf0));
            }
            __syncthreads();  // protect ring before next chunk overwrites
        }
    }
}

extern "C" void kernel_launch(void* const* d_in, const int* in_sizes, int n_in,
                              void* d_out, int out_size, void* d_ws, size_t ws_size,
                              hipStream_t stream) {
    const float* input = (const float*)d_in[0];
    // d_in[1] = target (unused by forward)
    const float* Wi = (const float*)d_in[2];
    const float* bi = (const float*)d_in[3];
    const float* Wh = (const float*)d_in[4];
    const float* bh = (const float*)d_in[5];
    const float* Wf = (const float*)d_in[6];
    const float* bf = (const float*)d_in[7];
    float* out = (float*)d_out;

    elman_kernel<<<dim3(BATCH), dim3(1024), 0, stream>>>(
        input, Wi, bi, Wh, bh, Wf, bf, out);
}

// Round 12
// 2289.708 us; speedup vs baseline: 1.0926x; 1.0926x over previous
//
#include <hip/hip_runtime.h>

#define T_STEPS 4096
#define BATCH   64
#define INDIM   4
#define H       256
#define OUTD    2
#define CHUNK   32
#define SLOT_DW 36                    // dwords per k-quarter: 32 + 4 skew
#define ENT_DW  (4*SLOT_DW)           // 144 dwords per stored h vector
#define ENT_B   (4*ENT_DW)            // 576 bytes
#define RING_DW (CHUNK*ENT_DW)        // 4608 dwords (18 KB)
#define DUMP_DW 256                   // 1 KB dump for non-writer lanes
#define WF_DW   (OUTD*(H/2))          // 256 dwords packed Wf
#define XS_DW   (CHUNK*INDIM)         // 128 dwords: staged x for the chunk

typedef __fp16 half2v __attribute__((ext_vector_type(2)));

__device__ __forceinline__ float fast_tanh(float x) {
    float ax = fabsf(x);
    float e  = __expf(-2.0f * ax);
    float r  = (1.0f - e) * __builtin_amdgcn_rcpf(1.0f + e);
    return copysignf(r, x);
}

template<int CTRL>
__device__ __forceinline__ float dpp_radd(float a) {
    int s = __builtin_amdgcn_update_dpp(0, __builtin_bit_cast(int, a),
                                        CTRL, 0xf, 0xf, true);
    return a + __builtin_bit_cast(float, s);
}
#define SHL1 0x101
#define SHL2 0x102
#define SHL4 0x104
#define SHL8 0x108
#define SHR1 0x111
#define SHR2 0x112

// R8 structure (best: 2294 us, weights resident at VGPR=88) with ONE change:
// no VMEM inside the step loop. R8 issued a global x-prefetch every step;
// the compiler's mandatory `s_waitcnt vmcnt(0)` before every s_barrier made
// each step eat the full global-load latency. x for the whole chunk is now
// staged into LDS once per 32 steps; steps read it via a broadcast
// ds_read_b128, so the per-step barrier drains nothing.
__global__ __attribute__((amdgpu_waves_per_eu(2, 2))) __launch_bounds__(512)
void elman_kernel(const float* __restrict__ input,
                  const float* __restrict__ Wi,
                  const float* __restrict__ bi,
                  const float* __restrict__ Wh,
                  const float* __restrict__ bh,
                  const float* __restrict__ Wf,
                  const float* __restrict__ bf,
                  float* __restrict__ out)
{
    const int b  = blockIdx.x;
    const int t  = threadIdx.x;
    const int rp = t >> 2;        // row pair 0..127
    const int ko = t & 3;         // k-quarter
    const int r0 = rp * 2, r1 = r0 + 1;
    const int k0 = ko * 64;

    __shared__ unsigned int lds[RING_DW + DUMP_DW + WF_DW + XS_DW];
    unsigned int* ring   = lds;
    unsigned int* wf_pk  = lds + RING_DW + DUMP_DW;
    float*        xstage = (float*)(lds + RING_DW + DUMP_DW + WF_DW);

    // --- weights: 2 rows x 64 k packed f16 -> 64 dwords (resident, R8) ---
    half2v w0[32], w1[32];
    {
        const float* p0 = Wh + (size_t)r0 * H + k0;
        const float* p1 = Wh + (size_t)r1 * H + k0;
        #pragma unroll
        for (int j = 0; j < 16; ++j) {
            float4 a = *(const float4*)(p0 + 4 * j);
            float4 c = *(const float4*)(p1 + 4 * j);
            w0[2 * j]     = __builtin_amdgcn_cvt_pkrtz(a.x, a.y);
            w0[2 * j + 1] = __builtin_amdgcn_cvt_pkrtz(a.z, a.w);
            w1[2 * j]     = __builtin_amdgcn_cvt_pkrtz(c.x, c.y);
            w1[2 * j + 1] = __builtin_amdgcn_cvt_pkrtz(c.z, c.w);
        }
    }
    #pragma unroll
    for (int j = 0; j < 32; ++j) {
        float f0 = __builtin_bit_cast(float, w0[j]);
        float f1 = __builtin_bit_cast(float, w1[j]);
        asm volatile("" : "+v"(f0), "+v"(f1));
        w0[j] = __builtin_bit_cast(half2v, f0);
        w1[j] = __builtin_bit_cast(half2v, f1);
    }

    // epilogue role: lane ko==0 finalizes row r0, lane ko==3 finalizes row r1
    const int  ko3      = (ko == 3);
    const int  row_mine = r0 + ko3;
    const int  is_wr    = (ko == 0) | ko3;
    const float4 wim    = *(const float4*)(Wi + row_mine * INDIM);
    const float  biasm  = bi[row_mine] + bh[row_mine];
    const float  bf0    = bf[0], bf1 = bf[1];
    const int  boff     = (row_mine >> 6) * (SLOT_DW * 4) + (row_mine & 63) * 2;
    const int  dumpoff  = RING_DW * 4 + t * 2;

    if (t < WF_DW) {
        const int o = t >> 7, e = t & 127;
        wf_pk[t] = __builtin_bit_cast(unsigned int,
            __builtin_amdgcn_cvt_pkrtz(Wf[o * H + 2 * e], Wf[o * H + 2 * e + 1]));
    }
    if (t < H / 2) ring[(CHUNK - 1) * ENT_DW + (t >> 5) * SLOT_DW + (t & 31)] = 0u;
    __syncthreads();

    const unsigned int rd_off = (unsigned int)(ko * SLOT_DW);

    for (int chunk = 0; chunk < T_STEPS / CHUNK; ++chunk) {
        // ---- stage this chunk's x into LDS (only VMEM reads per chunk) ----
        if (t < XS_DW) {
            const int s = chunk * CHUNK + (t >> 2);
            xstage[t] = input[((size_t)s * BATCH + b) * INDIM + (t & 3)];
        }
        __syncthreads();   // drains the staging loads ONCE per chunk

        #pragma unroll 1
        for (int i = 0; i < CHUNK; ++i) {
            const unsigned int* hb =
                ring + ((i + CHUNK - 1) & (CHUNK - 1)) * ENT_DW + rd_off;
            uint4 hv[8];
            #pragma unroll
            for (int j = 0; j < 8; ++j) hv[j] = *(const uint4*)(hb + 4 * j);
            // wave-uniform broadcast read of this step's x (no VMEM in loop)
            const float4 xs = *(const float4*)(xstage + 4 * i);

            float acc0 = 0.f, acc1 = 0.f;
            #pragma unroll
            for (int j = 0; j < 8; ++j) {
                half2v h0 = __builtin_bit_cast(half2v, hv[j].x);
                half2v h1 = __builtin_bit_cast(half2v, hv[j].y);
                half2v h2 = __builtin_bit_cast(half2v, hv[j].z);
                half2v h3 = __builtin_bit_cast(half2v, hv[j].w);
                acc0 = __builtin_amdgcn_fdot2(w0[4 * j],     h0, acc0, false);
                acc1 = __builtin_amdgcn_fdot2(w1[4 * j],     h0, acc1, false);
                acc0 = __builtin_amdgcn_fdot2(w0[4 * j + 1], h1, acc0, false);
                acc1 = __builtin_amdgcn_fdot2(w1[4 * j + 1], h1, acc1, false);
                acc0 = __builtin_amdgcn_fdot2(w0[4 * j + 2], h2, acc0, false);
                acc1 = __builtin_amdgcn_fdot2(w1[4 * j + 2], h2, acc1, false);
                acc0 = __builtin_amdgcn_fdot2(w0[4 * j + 3], h3, acc0, false);
                acc1 = __builtin_amdgcn_fdot2(w1[4 * j + 3], h3, acc1, false);
            }

            // DPP reduce over the 4-lane group: acc0 -> lane 0, acc1 -> lane 3
            acc0 = dpp_radd<SHL2>(acc0);
            acc0 = dpp_radd<SHL1>(acc0);
            acc1 = dpp_radd<SHR2>(acc1);
            acc1 = dpp_radd<SHR1>(acc1);

            // unmasked epilogue: every lane finalizes one row (2 of 4 valid)
            float accm = ko3 ? acc1 : acc0;
            float pre  = accm + biasm +
                xs.x * wim.x + xs.y * wim.y + xs.z * wim.z + xs.w * wim.w;
            __fp16 h16 = (__fp16)fast_tanh(pre);
            int waddr  = is_wr ? (i * ENT_B + boff) : dumpoff;
            *(__fp16*)((char*)lds + waddr) = h16;

            __syncthreads();   // drains nothing but the b16 write now
        }

        // --- deferred output head: 64 tasks x 8 lanes ---
        {
            const int task = t >> 3;
            const int s    = task >> 1;
            const int o    = task & 1;
            const int sub  = t & 7;
            const unsigned int* hp =
                ring + s * ENT_DW + (sub >> 1) * SLOT_DW + (sub & 1) * 16;
            const unsigned int* wp = wf_pk + o * (H / 2) + sub * 16;

            uint4 hA = *(const uint4*)(hp);
            uint4 hB = *(const uint4*)(hp + 4);
            uint4 hC = *(const uint4*)(hp + 8);
            uint4 hD = *(const uint4*)(hp + 12);
            uint4 wA = *(const uint4*)(wp);
            uint4 wB = *(const uint4*)(wp + 4);
            uint4 wC = *(const uint4*)(wp + 8);
            uint4 wD = *(const uint4*)(wp + 12);
            unsigned int hh[16] = {hA.x, hA.y, hA.z, hA.w, hB.x, hB.y, hB.z, hB.w,
                                   hC.x, hC.y, hC.z, hC.w, hD.x, hD.y, hD.z, hD.w};
            unsigned int ww[16] = {wA.x, wA.y, wA.z, wA.w, wB.x, wB.y, wB.z, wB.w,
                                   wC.x, wC.y, wC.z, wC.w, wD.x, wD.y, wD.z, wD.w};

            float acc = 0.f;
            #pragma unroll
            for (int j = 0; j < 16; ++j)
                acc = __builtin_amdgcn_fdot2(__builtin_bit_cast(half2v, ww[j]),
                                             __builtin_bit_cast(half2v, hh[j]),
                                             acc, false);
            acc = dpp_radd<SHL4>(acc);
            acc = dpp_radd<SHL2>(acc);
            acc = dpp_radd<SHL1>(acc);

            if (sub == 0) {
                out[((size_t)(chunk * CHUNK + s) * BATCH + b) * OUTD + o] =
                    fast_tanh(acc + (o ? bf1 : bf0));
            }
            __syncthreads();  // protect ring before next chunk overwrites
        }
    }
}

extern "C" void kernel_launch(void* const* d_in, const int* in_sizes, int n_in,
                              void* d_out, int out_size, void* d_ws, size_t ws_size,
                              hipStream_t stream) {
    const float* input = (const float*)d_in[0];
    // d_in[1] = target (unused by forward)
    const float* Wi = (const float*)d_in[2];
    const float* bi = (const float*)d_in[3];
    const float* Wh = (const float*)d_in[4];
    const float* bh = (const float*)d_in[5];
    const float* Wf = (const float*)d_in[6];
    const float* bf = (const float*)d_in[7];
    float* out = (float*)d_out;

    elman_kernel<<<dim3(BATCH), dim3(512), 0, stream>>>(
        input, Wi, bi, Wh, bh, Wf, bf, out);
}